// Round 2
// baseline (1276.998 us; speedup 1.0000x reference)
//
#include <hip/hip_runtime.h>
#include <hip/hip_bf16.h>

#define CC 128
#define NOUT 384
#define PI_F 3.14159265358979323846f
#define RCUT 5.0f

// ---------------------------------------------------------------------------
// Dtype-agnostic loads: flags discovered on-device (graph-safe, same work
// every call).  isf32: float tensors stored as f32 (else bf16).
// isi64: edges stored as int64 (else int32).
// ---------------------------------------------------------------------------
__device__ __forceinline__ float loadF(const void* p, size_t i, int isf32) {
  if (isf32) return ((const float*)p)[i];
  unsigned int w = ((unsigned int)((const unsigned short*)p)[i]) << 16;
  return __uint_as_float(w);
}
__device__ __forceinline__ int loadI(const void* p, size_t i, int isi64) {
  if (isi64) return (int)((const long long*)p)[i];
  return ((const int*)p)[i];
}

__global__ void detect_kernel(const void* s, const void* edges, int* flags) {
  if (threadIdx.x == 0) {
    // float dtype probe: read s as bf16; real bf16 N(0,1) stays < ~6,
    // f32-misread garbage hits |x|>1000 or NaN with ~certainty in 1024 tries.
    int isf32 = 0;
    const unsigned short* us = (const unsigned short*)s;
    for (int i = 0; i < 1024; i++) {
      unsigned int w = ((unsigned int)us[i]) << 16;
      float f = __uint_as_float(w);
      if (!(fabsf(f) < 1000.f)) { isf32 = 1; break; }  // catches NaN too
    }
    // int width probe: int64 node indices (<2^31) have zero high words at
    // every odd int32 position; int32 src values are ~never all zero.
    int isi64 = 1;
    const int* ie = (const int*)edges;
    for (int i = 1; i < 128; i += 2) {
      if (ie[i] != 0) { isi64 = 0; break; }
    }
    flags[0] = isf32;
    flags[1] = isi64;
  }
}

// ---------------------------------------------------------------------------
// Kernel 1: s_pass[n, 0:384] = silu(s[n,:] @ W1 + b1) @ W2 + b2  (bf16 out)
// 8 nodes per 128-thread block so W1/W2 traffic is amortized 8x.
// ---------------------------------------------------------------------------
__global__ __launch_bounds__(128) void node_mlp_kernel(
    const void* __restrict__ s,
    const void* __restrict__ W1, const void* __restrict__ b1,
    const void* __restrict__ W2, const void* __restrict__ b2,
    __hip_bfloat16* __restrict__ s_pass, const int* __restrict__ flags, int N) {
  const int isf32 = flags[0];
  const int M = 8;
  __shared__ float s_sh[M][CC];
  __shared__ float h_sh[M][CC];
  const int c = threadIdx.x;
  const int n0 = blockIdx.x * M;

  #pragma unroll
  for (int m = 0; m < M; m++) {
    int n = n0 + m;
    s_sh[m][c] = (n < N) ? loadF(s, (size_t)n * CC + c, isf32) : 0.f;
  }
  __syncthreads();

  float acc[M];
  #pragma unroll
  for (int m = 0; m < M; m++) acc[m] = 0.f;
  for (int k = 0; k < CC; k++) {
    float w = loadF(W1, (size_t)k * CC + c, isf32);
    #pragma unroll
    for (int m = 0; m < M; m++) acc[m] += s_sh[m][k] * w;
  }
  float bb1 = loadF(b1, c, isf32);
  #pragma unroll
  for (int m = 0; m < M; m++) {
    float x = acc[m] + bb1;
    h_sh[m][c] = x / (1.f + __expf(-x));   // silu
  }
  __syncthreads();

  #pragma unroll
  for (int jj = 0; jj < 3; jj++) {
    int j = jj * CC + c;
    float a2[M];
    #pragma unroll
    for (int m = 0; m < M; m++) a2[m] = 0.f;
    for (int k = 0; k < CC; k++) {
      float w = loadF(W2, (size_t)k * NOUT + j, isf32);
      #pragma unroll
      for (int m = 0; m < M; m++) a2[m] += h_sh[m][k] * w;
    }
    float bb2 = loadF(b2, j, isf32);
    #pragma unroll
    for (int m = 0; m < M; m++) {
      int n = n0 + m;
      if (n < N) s_pass[(size_t)n * NOUT + j] = __float2bfloat16(a2[m] + bb2);
    }
  }
}

// ---------------------------------------------------------------------------
// Kernel 2: per-edge; one block = one edge, 128 threads = channel dim.
// ---------------------------------------------------------------------------
__global__ __launch_bounds__(128) void edge_kernel(
    const void* __restrict__ v, const void* __restrict__ edges,
    const void* __restrict__ r_ij, const void* __restrict__ rn,
    const void* __restrict__ Wr, const void* __restrict__ br,
    const __hip_bfloat16* __restrict__ s_pass,
    float* __restrict__ s_acc, float* __restrict__ v_acc,
    const int* __restrict__ flags, int E) {
  const int e = blockIdx.x;
  if (e >= E) return;
  const int isf32 = flags[0];
  const int isi64 = flags[1];
  __shared__ float rbfv[20];

  const int c = threadIdx.x;
  const int dst = loadI(edges, (size_t)2 * e + 0, isi64);
  const int src = loadI(edges, (size_t)2 * e + 1, isi64);
  const float r = loadF(r_ij, e, isf32);

  if (c < 20) {
    float n = (float)(c + 1);
    rbfv[c] = __sinf((PI_F / RCUT) * n * r) / r;
  }
  __syncthreads();

  const float fc = 0.5f * (__cosf(PI_F * r / RCUT) + 1.f);

  float pj[3];
  #pragma unroll
  for (int jj = 0; jj < 3; jj++) {
    int j = jj * CC + c;
    float a = loadF(br, j, isf32);
    #pragma unroll
    for (int n = 0; n < 20; n++) a += rbfv[n] * loadF(Wr, (size_t)n * NOUT + j, isf32);
    pj[jj] = a * fc * __bfloat162float(s_pass[(size_t)src * NOUT + j]);
  }
  const float dv = pj[0], ds = pj[1], drep = pj[2];

  atomicAdd(&s_acc[(size_t)dst * CC + c], ds);
  #pragma unroll
  for (int d = 0; d < 3; d++) {
    float rr = loadF(rn, (size_t)e * 3 + d, isf32);
    float vv = loadF(v, (size_t)src * NOUT + d * CC + c, isf32);
    atomicAdd(&v_acc[(size_t)dst * NOUT + d * CC + c], vv * dv + rr * drep);
  }
}

// ---------------------------------------------------------------------------
// Kernel 3: out = concat(s + s_acc, v + v_acc), dtype matches inputs.
// ---------------------------------------------------------------------------
__global__ __launch_bounds__(256) void finalize_kernel(
    const void* __restrict__ s, const void* __restrict__ v,
    const float* __restrict__ s_acc, const float* __restrict__ v_acc,
    void* __restrict__ out, const int* __restrict__ flags, int N) {
  const int isf32 = flags[0];
  const long long total = (long long)N * 512;
  const long long ns = (long long)N * CC;
  long long i = (long long)blockIdx.x * blockDim.x + threadIdx.x;
  if (i >= total) return;
  float val;
  if (i < ns) {
    val = loadF(s, i, isf32) + s_acc[i];
  } else {
    long long k = i - ns;
    val = loadF(v, k, isf32) + v_acc[k];
  }
  if (isf32) ((float*)out)[i] = val;
  else ((__hip_bfloat16*)out)[i] = __float2bfloat16(val);
}

extern "C" void kernel_launch(void* const* d_in, const int* in_sizes, int n_in,
                              void* d_out, int out_size, void* d_ws, size_t ws_size,
                              hipStream_t stream) {
  const void* s     = d_in[0];
  const void* v     = d_in[1];
  const void* edges = d_in[2];
  const void* r_ij  = d_in[3];
  const void* rn    = d_in[4];
  const void* W1    = d_in[5];
  const void* b1    = d_in[6];
  const void* W2    = d_in[7];
  const void* b2    = d_in[8];
  const void* Wr    = d_in[9];
  const void* br    = d_in[10];

  const int N = in_sizes[0] / CC;     // 50000
  const int E = in_sizes[3];          // 400000

  // ws layout: [flags 256B][s_pass bf16 N*384][s_acc f32 N*128][v_acc f32 N*384]
  char* ws = (char*)d_ws;
  int* flags = (int*)ws;
  __hip_bfloat16* s_pass = (__hip_bfloat16*)(ws + 256);
  size_t off_acc = 256 + (size_t)N * NOUT * sizeof(__hip_bfloat16);  // 256-aligned
  float* s_acc = (float*)(ws + off_acc);
  float* v_acc = s_acc + (size_t)N * CC;

  // zero both accumulators (contiguous N*512 floats)
  hipMemsetAsync(s_acc, 0, (size_t)N * 512 * sizeof(float), stream);

  detect_kernel<<<1, 64, 0, stream>>>(s, edges, flags);
  node_mlp_kernel<<<(N + 7) / 8, 128, 0, stream>>>(s, W1, b1, W2, b2, s_pass,
                                                   flags, N);
  edge_kernel<<<E, 128, 0, stream>>>(v, edges, r_ij, rn, Wr, br, s_pass,
                                     s_acc, v_acc, flags, E);
  const long long total = (long long)N * 512;
  finalize_kernel<<<(int)((total + 255) / 256), 256, 0, stream>>>(
      s, v, s_acc, v_acc, d_out, flags, N);
}

// Round 3
// 867.556 us; speedup vs baseline: 1.4719x; 1.4719x over previous
//
#include <hip/hip_runtime.h>
#include <hip/hip_bf16.h>

#define CC 128
#define NOUT 384
#define PI_F 3.14159265358979323846f
#define RCUT 5.0f

// ---------------------------------------------------------------------------
// Dtype-agnostic loads (flags discovered on device; graph-safe).
// ---------------------------------------------------------------------------
__device__ __forceinline__ float loadF(const void* p, size_t i, int isf32) {
  if (isf32) return ((const float*)p)[i];
  unsigned int w = ((unsigned int)((const unsigned short*)p)[i]) << 16;
  return __uint_as_float(w);
}
__device__ __forceinline__ int loadI(const void* p, size_t i, int isi64) {
  if (isi64) return (int)((const long long*)p)[i];
  return ((const int*)p)[i];
}

__global__ void detect_kernel(const void* s, const void* edges, int* flags) {
  if (threadIdx.x == 0) {
    int isf32 = 0;
    const unsigned short* us = (const unsigned short*)s;
    for (int i = 0; i < 1024; i++) {
      unsigned int w = ((unsigned int)us[i]) << 16;
      float f = __uint_as_float(w);
      if (!(fabsf(f) < 1000.f)) { isf32 = 1; break; }
    }
    int isi64 = 1;
    const int* ie = (const int*)edges;
    for (int i = 1; i < 128; i += 2) {
      if (ie[i] != 0) { isi64 = 0; break; }
    }
    flags[0] = isf32;
    flags[1] = isi64;
  }
}

// ---------------------------------------------------------------------------
// CSR build: count -> scan -> fill
// ---------------------------------------------------------------------------
__global__ void count_kernel(const void* __restrict__ edges, int* __restrict__ cnt,
                             const int* __restrict__ flags, int E) {
  int e = blockIdx.x * blockDim.x + threadIdx.x;
  if (e >= E) return;
  int dst = loadI(edges, (size_t)2 * e, flags[1]);
  atomicAdd(&cnt[dst], 1);
}

__global__ __launch_bounds__(1024) void scan_kernel(const int* __restrict__ cnt,
                                                    int* __restrict__ row_start,
                                                    int* __restrict__ next, int N) {
  __shared__ int buf[1024];
  __shared__ int carry_sh;
  const int t = threadIdx.x;
  if (t == 0) carry_sh = 0;
  __syncthreads();
  for (int base = 0; base < N; base += 1024) {
    int x = (base + t < N) ? cnt[base + t] : 0;
    buf[t] = x;
    __syncthreads();
    for (int off = 1; off < 1024; off <<= 1) {
      int tmp = (t >= off) ? buf[t - off] : 0;
      __syncthreads();
      buf[t] += tmp;
      __syncthreads();
    }
    int incl = buf[t];
    int carry = carry_sh;
    int excl = carry + incl - x;
    if (base + t < N) { row_start[base + t] = excl; next[base + t] = excl; }
    int total = buf[1023];
    __syncthreads();
    if (t == 0) carry_sh = carry + total;
    __syncthreads();
  }
  if (t == 0) row_start[N] = carry_sh;
}

__global__ void fill_kernel(const void* __restrict__ edges, int* __restrict__ next,
                            int* __restrict__ perm, const int* __restrict__ flags, int E) {
  int e = blockIdx.x * blockDim.x + threadIdx.x;
  if (e >= E) return;
  int dst = loadI(edges, (size_t)2 * e, flags[1]);
  int p = atomicAdd(&next[dst], 1);
  perm[p] = e;
}

// ---------------------------------------------------------------------------
// Node MLP: s_pass = silu(s@W1+b1)@W2+b2  (bf16 out); 8 nodes/block.
// ---------------------------------------------------------------------------
__global__ __launch_bounds__(128) void node_mlp_kernel(
    const void* __restrict__ s,
    const void* __restrict__ W1, const void* __restrict__ b1,
    const void* __restrict__ W2, const void* __restrict__ b2,
    __hip_bfloat16* __restrict__ s_pass, const int* __restrict__ flags, int N) {
  const int isf32 = flags[0];
  const int M = 8;
  __shared__ float s_sh[M][CC];
  __shared__ float h_sh[M][CC];
  const int c = threadIdx.x;
  const int n0 = blockIdx.x * M;

  #pragma unroll
  for (int m = 0; m < M; m++) {
    int n = n0 + m;
    s_sh[m][c] = (n < N) ? loadF(s, (size_t)n * CC + c, isf32) : 0.f;
  }
  __syncthreads();

  float acc[M];
  #pragma unroll
  for (int m = 0; m < M; m++) acc[m] = 0.f;
  for (int k = 0; k < CC; k++) {
    float w = loadF(W1, (size_t)k * CC + c, isf32);
    #pragma unroll
    for (int m = 0; m < M; m++) acc[m] += s_sh[m][k] * w;
  }
  float bb1 = loadF(b1, c, isf32);
  #pragma unroll
  for (int m = 0; m < M; m++) {
    float x = acc[m] + bb1;
    h_sh[m][c] = x / (1.f + __expf(-x));
  }
  __syncthreads();

  #pragma unroll
  for (int jj = 0; jj < 3; jj++) {
    int j = jj * CC + c;
    float a2[M];
    #pragma unroll
    for (int m = 0; m < M; m++) a2[m] = 0.f;
    for (int k = 0; k < CC; k++) {
      float w = loadF(W2, (size_t)k * NOUT + j, isf32);
      #pragma unroll
      for (int m = 0; m < M; m++) a2[m] += h_sh[m][k] * w;
    }
    float bb2 = loadF(b2, j, isf32);
    #pragma unroll
    for (int m = 0; m < M; m++) {
      int n = n0 + m;
      if (n < N) s_pass[(size_t)n * NOUT + j] = __float2bfloat16(a2[m] + bb2);
    }
  }
}

// ---------------------------------------------------------------------------
// Per-node gather-aggregate: one block per dst node, 128 threads = channels.
// Accumulates all incoming edges in registers; writes out = residual + acc.
// No atomics, no f32 accumulator arrays, no finalize pass.
// ---------------------------------------------------------------------------
__global__ __launch_bounds__(128) void aggregate_kernel(
    const void* __restrict__ s, const void* __restrict__ v,
    const void* __restrict__ edges, const void* __restrict__ r_ij,
    const void* __restrict__ rn, const void* __restrict__ Wr,
    const void* __restrict__ br, const __hip_bfloat16* __restrict__ s_pass,
    const int* __restrict__ row_start, const int* __restrict__ perm,
    void* __restrict__ out, const int* __restrict__ flags, int N) {
  const int isf32 = flags[0];
  const int isi64 = flags[1];
  const int n = blockIdx.x;
  const int c = threadIdx.x;

  // Hoist Wr columns for this channel (L1-hit loads, once per block).
  float w0[20], w1[20], w2[20];
  #pragma unroll
  for (int k = 0; k < 20; k++) {
    w0[k] = loadF(Wr, (size_t)k * NOUT + c, isf32);
    w1[k] = loadF(Wr, (size_t)k * NOUT + CC + c, isf32);
    w2[k] = loadF(Wr, (size_t)k * NOUT + 2 * CC + c, isf32);
  }
  const float b0 = loadF(br, c, isf32);
  const float b1v = loadF(br, CC + c, isf32);
  const float b2v = loadF(br, 2 * CC + c, isf32);

  float accs = 0.f, accv0 = 0.f, accv1 = 0.f, accv2 = 0.f;
  const int beg = row_start[n], end = row_start[n + 1];
  for (int i = beg; i < end; i++) {
    const int e = perm[i];
    const int src = loadI(edges, (size_t)2 * e + 1, isi64);
    const float r = loadF(r_ij, e, isf32);
    const float x = (PI_F / RCUT) * r;
    const float s1 = __sinf(x);
    const float c1 = __cosf(x);
    const float fc = 0.5f * (c1 + 1.f);
    const float rinv = __builtin_amdgcn_rcpf(r);
    const float twoc = 2.f * c1;

    // rbf via Chebyshev recurrence: sin((k+1)x) = 2cos(x)sin(kx) - sin((k-1)x)
    float a0 = b0, a1 = b1v, a2 = b2v;
    float sp = 0.f, sn = s1;
    #pragma unroll
    for (int k = 0; k < 20; k++) {
      float rb = sn * rinv;
      a0 += rb * w0[k];
      a1 += rb * w1[k];
      a2 += rb * w2[k];
      float s2 = twoc * sn - sp;
      sp = sn; sn = s2;
    }

    const size_t sb = (size_t)src * NOUT;
    const float p0 = a0 * fc * __bfloat162float(s_pass[sb + c]);
    const float p1 = a1 * fc * __bfloat162float(s_pass[sb + CC + c]);
    const float p2 = a2 * fc * __bfloat162float(s_pass[sb + 2 * CC + c]);

    accs += p1;
    const float r0 = loadF(rn, (size_t)e * 3 + 0, isf32);
    const float r1 = loadF(rn, (size_t)e * 3 + 1, isf32);
    const float r2 = loadF(rn, (size_t)e * 3 + 2, isf32);
    accv0 += loadF(v, sb + 0 * CC + c, isf32) * p0 + r0 * p2;
    accv1 += loadF(v, sb + 1 * CC + c, isf32) * p0 + r1 * p2;
    accv2 += loadF(v, sb + 2 * CC + c, isf32) * p0 + r2 * p2;
  }

  const size_t si = (size_t)n * CC + c;
  const size_t vi = (size_t)n * NOUT;
  const float so = loadF(s, si, isf32) + accs;
  const float o0 = loadF(v, vi + 0 * CC + c, isf32) + accv0;
  const float o1 = loadF(v, vi + 1 * CC + c, isf32) + accv1;
  const float o2 = loadF(v, vi + 2 * CC + c, isf32) + accv2;
  const size_t vo = (size_t)N * CC + vi;
  if (isf32) {
    float* o = (float*)out;
    o[si] = so;
    o[vo + 0 * CC + c] = o0;
    o[vo + 1 * CC + c] = o1;
    o[vo + 2 * CC + c] = o2;
  } else {
    __hip_bfloat16* o = (__hip_bfloat16*)out;
    o[si] = __float2bfloat16(so);
    o[vo + 0 * CC + c] = __float2bfloat16(o0);
    o[vo + 1 * CC + c] = __float2bfloat16(o1);
    o[vo + 2 * CC + c] = __float2bfloat16(o2);
  }
}

extern "C" void kernel_launch(void* const* d_in, const int* in_sizes, int n_in,
                              void* d_out, int out_size, void* d_ws, size_t ws_size,
                              hipStream_t stream) {
  const void* s     = d_in[0];
  const void* v     = d_in[1];
  const void* edges = d_in[2];
  const void* r_ij  = d_in[3];
  const void* rn    = d_in[4];
  const void* W1    = d_in[5];
  const void* b1    = d_in[6];
  const void* W2    = d_in[7];
  const void* b2    = d_in[8];
  const void* Wr    = d_in[9];
  const void* br    = d_in[10];

  const int N = in_sizes[0] / CC;     // 50000
  const int E = in_sizes[3];          // 400000

  // ws layout: flags | s_pass (bf16 N*384) | cnt | row_start | next | perm
  char* ws = (char*)d_ws;
  int* flags = (int*)ws;
  __hip_bfloat16* s_pass = (__hip_bfloat16*)(ws + 256);
  char* p = ws + 256 + (size_t)N * NOUT * sizeof(__hip_bfloat16);
  int* cnt       = (int*)p;            p += (size_t)N * sizeof(int);
  int* row_start = (int*)p;            p += (size_t)(N + 1) * sizeof(int);
  int* next      = (int*)p;            p += (size_t)N * sizeof(int);
  int* perm      = (int*)p;

  hipMemsetAsync(cnt, 0, (size_t)N * sizeof(int), stream);

  detect_kernel<<<1, 64, 0, stream>>>(s, edges, flags);
  count_kernel<<<(E + 255) / 256, 256, 0, stream>>>(edges, cnt, flags, E);
  scan_kernel<<<1, 1024, 0, stream>>>(cnt, row_start, next, N);
  fill_kernel<<<(E + 255) / 256, 256, 0, stream>>>(edges, next, perm, flags, E);
  node_mlp_kernel<<<(N + 7) / 8, 128, 0, stream>>>(s, W1, b1, W2, b2, s_pass,
                                                   flags, N);
  aggregate_kernel<<<N, 128, 0, stream>>>(s, v, edges, r_ij, rn, Wr, br,
                                          s_pass, row_start, perm, d_out,
                                          flags, N);
}